// Round 2
// baseline (123.836 us; speedup 1.0000x reference)
//
#include <hip/hip_runtime.h>

// GWD loss: pred(N,5) f32, target(N,5) f32, weight(N) f32 -> scalar mean.
// Closed-form per-row math. Round 2: coalesced float4 staging through LDS
// (stride-5 AoS rows defeat per-instruction coalescing when read directly).
// FUN='log', TAU=1.0, ALPHA=1.0, LOSS_WEIGHT=1.0.

#define ROWS_PER_CHUNK 512   // floats per chunk: 512*5 = 2560 (16B-aligned chunks)

__global__ __launch_bounds__(256) void gwd_loss_kernel(
    const float* __restrict__ pred,
    const float* __restrict__ target,
    const float* __restrict__ weight,
    float* __restrict__ out,
    int n)
{
    // 22.5 KB LDS -> 7 blocks/CU (LDS-capped), 28 waves/CU
    __shared__ float s_pred[ROWS_PER_CHUNK * 5];
    __shared__ float s_tgt [ROWS_PER_CHUNK * 5];
    __shared__ float s_w   [ROWS_PER_CHUNK];

    const float inv_n = 1.0f / (float)n;
    float acc = 0.0f;

    const int n_chunks = (n + ROWS_PER_CHUNK - 1) / ROWS_PER_CHUNK;

    for (int chunk = blockIdx.x; chunk < n_chunks; chunk += gridDim.x) {
        const int row0 = chunk * ROWS_PER_CHUNK;
        const int rows = min(ROWS_PER_CHUNK, n - row0);

        // ---- stage: perfectly coalesced float4 loads ----
        // row0*5 = chunk*2560, divisible by 4 -> float4-aligned base.
        const int nf4 = (rows * 5 + 3) >> 2;   // tail: 128*5=640 -> exact
        const float4* p4 = (const float4*)(pred   + (size_t)row0 * 5);
        const float4* t4 = (const float4*)(target + (size_t)row0 * 5);
        for (int j = threadIdx.x; j < nf4; j += 256) {
            ((float4*)s_pred)[j] = p4[j];
            ((float4*)s_tgt )[j] = t4[j];
        }
        const int nw4 = (rows + 3) >> 2;
        const float4* w4 = (const float4*)(weight + row0);
        for (int j = threadIdx.x; j < nw4; j += 256)
            ((float4*)s_w)[j] = w4[j];
        __syncthreads();

        // ---- compute: 2 rows/thread; LDS lane-stride 5 (gcd(5,32)=1 -> conflict-free) ----
        #pragma unroll
        for (int rr = 0; rr < ROWS_PER_CHUNK / 256; ++rr) {
            const int r = threadIdx.x + rr * 256;
            if (r < rows) {
                const float* pp = &s_pred[r * 5];
                const float* tt = &s_tgt [r * 5];
                const float px = pp[0], py = pp[1], pw = pp[2], ph = pp[3], pr = pp[4];
                const float tx = tt[0], ty = tt[1], tw = tt[2], th = tt[3], trr_ = tt[4];

                const float dx = px - tx;
                const float dy = py - ty;
                const float xy_dist = dx * dx + dy * dy;

                const float a2p = 0.25f * pw * pw;
                const float b2p = 0.25f * ph * ph;
                const float a2t = 0.25f * tw * tw;
                const float b2t = 0.25f * th * th;

                float whr = (a2p + b2p) + (a2t + b2t);

                float cp, sp, ct, st;
                __sincosf(pr,  &sp, &cp);
                __sincosf(trr_, &st, &ct);

                const float Sp00 = cp * cp * a2p + sp * sp * b2p;
                const float Sp01 = cp * sp * (a2p - b2p);
                const float Sp11 = sp * sp * a2p + cp * cp * b2p;
                const float St00 = ct * ct * a2t + st * st * b2t;
                const float St01 = ct * st * (a2t - b2t);
                const float St11 = st * st * a2t + ct * ct * b2t;

                // tr(Sp^1/2 St Sp^1/2) = tr(Sp St); det(cross) = det(Sp)det(St)
                const float tr_cross  = Sp00 * St00 + 2.0f * Sp01 * St01 + Sp11 * St11;
                const float det_cross = (a2p * b2p) * (a2t * b2t);

                float sq = tr_cross + 2.0f * sqrtf(det_cross);
                sq = fmaxf(sq, 0.0f);
                whr = whr - 2.0f * sqrtf(sq);

                float dist2 = fmaxf(xy_dist + whr, 0.0f);   // ALPHA = 1
                float distance = sqrtf(dist2);

                const float prod = (pw * tw) * (ph * th);
                distance = distance / sqrtf(sqrtf(prod));   // / (prod)^(1/4)

                distance = log1pf(distance);                // FUN = 'log'
                const float loss = 1.0f - 1.0f / (1.0f + distance);  // TAU = 1

                acc += loss * s_w[r];
            }
        }
        __syncthreads();   // protect LDS before next chunk's staging
    }

    // ---- wave-64 -> block -> global reduction ----
    #pragma unroll
    for (int off = 32; off > 0; off >>= 1)
        acc += __shfl_down(acc, off, 64);

    __shared__ float wave_sums[4];
    const int lane = threadIdx.x & 63;
    const int wid  = threadIdx.x >> 6;
    if (lane == 0) wave_sums[wid] = acc;
    __syncthreads();

    if (threadIdx.x == 0) {
        const float s = (wave_sums[0] + wave_sums[1]) + (wave_sums[2] + wave_sums[3]);
        atomicAdd(out, s * inv_n);   // LOSS_WEIGHT = 1
    }
}

extern "C" void kernel_launch(void* const* d_in, const int* in_sizes, int n_in,
                              void* d_out, int out_size, void* d_ws, size_t ws_size,
                              hipStream_t stream) {
    const float* pred   = (const float*)d_in[0];
    const float* target = (const float*)d_in[1];
    const float* weight = (const float*)d_in[2];
    float* out = (float*)d_out;

    const int n = in_sizes[2];   // weight has N elements

    // harness poisons d_out with 0xAA before every timed launch
    hipMemsetAsync(out, 0, sizeof(float), stream);

    const int block = 256;
    const int grid  = 1792;   // 7 blocks/CU (LDS-capped occupancy), grid-stride over chunks
    gwd_loss_kernel<<<grid, block, 0, stream>>>(pred, target, weight, out, n);
}